// Round 1
// baseline (3546.054 us; speedup 1.0000x reference)
//
#include <hip/hip_runtime.h>

#define HD __device__ __forceinline__

HD float readlane_f(float v, int l) {
    return __int_as_float(__builtin_amdgcn_readlane(__float_as_int(v), l));
}

// ---------------- generic fp32 tiled GEMM: C[M,N] = A[M,K] @ B[K,N] ----------------
// requires N % 64 == 0, K % 16 == 0
__global__ __launch_bounds__(256) void gemm64_f32(const float* __restrict__ A,
                                                  const float* __restrict__ B,
                                                  float* __restrict__ C,
                                                  int M, int K, int N) {
    __shared__ float As[64 * 16];
    __shared__ float Bs[16 * 64];
    int tx = threadIdx.x & 15, ty = threadIdx.x >> 4;
    int rowBase = blockIdx.y * 64, colBase = blockIdx.x * 64;
    float acc[4][4] = {};
    for (int k0 = 0; k0 < K; k0 += 16) {
        for (int i = threadIdx.x; i < 64 * 16; i += 256) {
            int r = i >> 4, c = i & 15;
            int gr = rowBase + r;
            As[i] = (gr < M) ? A[(long)gr * K + k0 + c] : 0.f;
        }
        for (int i = threadIdx.x; i < 16 * 64; i += 256) {
            int r = i >> 6, c = i & 63;
            Bs[i] = B[(long)(k0 + r) * N + colBase + c];
        }
        __syncthreads();
#pragma unroll
        for (int kk = 0; kk < 16; ++kk) {
            float a[4], b[4];
#pragma unroll
            for (int i = 0; i < 4; ++i) a[i] = As[(ty * 4 + i) * 16 + kk];
#pragma unroll
            for (int j = 0; j < 4; ++j) b[j] = Bs[kk * 64 + tx * 4 + j];
#pragma unroll
            for (int i = 0; i < 4; ++i)
#pragma unroll
                for (int j = 0; j < 4; ++j) acc[i][j] += a[i] * b[j];
        }
        __syncthreads();
    }
    for (int i = 0; i < 4; ++i) {
        int gr = rowBase + ty * 4 + i;
        if (gr < M)
            for (int j = 0; j < 4; ++j)
                C[(long)gr * N + colBase + tx * 4 + j] = acc[i][j];
    }
}

// ---------------- degree / normalization ----------------
__global__ void deg_init(float* degI, float* degD, int N) {
    int i = blockIdx.x * 256 + threadIdx.x;
    if (i < N) { degI[i] = 1.f; degD[i] = 1.f; }
}

__global__ void count_edges(const int* __restrict__ dst, float* deg, int E) {
    int e = blockIdx.x * 256 + threadIdx.x;
    if (e < E) atomicAdd(&deg[dst[e]], 1.f);
}

__global__ void to_dinv(float* degI, float* degD, int N) {
    int i = blockIdx.x * 256 + threadIdx.x;
    if (i < N) { degI[i] = rsqrtf(degI[i]); degD[i] = rsqrtf(degD[i]); }
}

// ---------------- aggregation ----------------
// self-loop term: A[j] = xl[j] * dinv[j]^2   (for both graphs in one pass)
__global__ void init_self(const float* __restrict__ xl, const float* __restrict__ dI,
                          const float* __restrict__ dD, float* AI, float* AD, int N) {
    int t = blockIdx.x * 256 + threadIdx.x;
    int i = t >> 5, f4 = t & 31;
    if (i >= N) return;
    float4 v = ((const float4*)(xl + (long)i * 128))[f4];
    float a = dI[i]; a = a * a;
    float b = dD[i]; b = b * b;
    float4 vi = {v.x * a, v.y * a, v.z * a, v.w * a};
    float4 vd = {v.x * b, v.y * b, v.z * b, v.w * b};
    ((float4*)(AI + (long)i * 128))[f4] = vi;
    ((float4*)(AD + (long)i * 128))[f4] = vd;
}

// per edge (s->d): A[d] += dinv[s]*dinv[d] * xl[s]
__global__ void scatter_edges(const float* __restrict__ xl, const int* __restrict__ src,
                              const int* __restrict__ dst, const float* __restrict__ dinv,
                              float* A, int E) {
    int t = blockIdx.x * 256 + threadIdx.x;
    int e = t >> 5, f4 = t & 31;
    if (e >= E) return;
    int s = src[e], d = dst[e];
    float c = dinv[s] * dinv[d];
    float4 v = ((const float4*)(xl + (long)s * 128))[f4];
    float* base = A + (long)d * 128 + f4 * 4;
    atomicAdd(base + 0, c * v.x);
    atomicAdd(base + 1, c * v.y);
    atomicAdd(base + 2, c * v.z);
    atomicAdd(base + 3, c * v.w);
}

// z = relu(AI + b) + relu(AD + b)
__global__ void z_combine(const float* __restrict__ AI, const float* __restrict__ AD,
                          const float* __restrict__ bconv, float* z, int N) {
    int t = blockIdx.x * 256 + threadIdx.x;
    int i = t >> 5, f4 = t & 31;
    if (i >= N) return;
    float4 b = ((const float4*)bconv)[f4];
    float4 ai = ((const float4*)(AI + (long)i * 128))[f4];
    float4 ad = ((const float4*)(AD + (long)i * 128))[f4];
    float4 r;
    r.x = fmaxf(ai.x + b.x, 0.f) + fmaxf(ad.x + b.x, 0.f);
    r.y = fmaxf(ai.y + b.y, 0.f) + fmaxf(ad.y + b.y, 0.f);
    r.z = fmaxf(ai.z + b.z, 0.f) + fmaxf(ad.z + b.z, 0.f);
    r.w = fmaxf(ai.w + b.w, 0.f) + fmaxf(ad.w + b.w, 0.f);
    ((float4*)(z + (long)i * 128))[f4] = r;
}

// ---------------- decode ----------------
// out[p] = relu(U[i] + V[j] + |z_i - z_j| @ W1c + b1) @ W2 + b2
// one wave handles 2 pairs; W1c (rows 256..383 of W1) staged in 64KB LDS.
__global__ __launch_bounds__(256) void decode_kernel(
    const float* __restrict__ U, const float* __restrict__ V, const float* __restrict__ z,
    const int* __restrict__ ei, const int* __restrict__ ej,
    const float* __restrict__ W1, const float* __restrict__ b1,
    const float* __restrict__ W2, const float* __restrict__ b2,
    float* __restrict__ out, int P) {
    __shared__ float Wc[128 * 128];
    for (int i = threadIdx.x; i < 128 * 128; i += 256) Wc[i] = W1[256 * 128 + i];
    __syncthreads();
    int lane = threadIdx.x & 63;
    int wid = blockIdx.x * 4 + (threadIdx.x >> 6);
    int nw = gridDim.x * 4;
    float b1a = b1[lane], b1b = b1[lane + 64];
    float w2a = W2[lane], w2b = W2[lane + 64];
    float b2v = b2[0];
    for (int base = wid * 2; base < P; base += nw * 2) {
        int p0 = base, p1 = base + 1;
        bool has1 = p1 < P;
        int i0 = ei[p0], j0 = ej[p0];
        int i1 = has1 ? ei[p1] : i0, j1 = has1 ? ej[p1] : j0;
        float zi0a = z[i0 * 128 + lane], zi0b = z[i0 * 128 + lane + 64];
        float zj0a = z[j0 * 128 + lane], zj0b = z[j0 * 128 + lane + 64];
        float zi1a = z[i1 * 128 + lane], zi1b = z[i1 * 128 + lane + 64];
        float zj1a = z[j1 * 128 + lane], zj1b = z[j1 * 128 + lane + 64];
        float d0a = fabsf(zi0a - zj0a), d0b = fabsf(zi0b - zj0b);
        float d1a = fabsf(zi1a - zj1a), d1b = fabsf(zi1b - zj1b);
        float acc0a = U[i0 * 128 + lane] + V[j0 * 128 + lane] + b1a;
        float acc0b = U[i0 * 128 + lane + 64] + V[j0 * 128 + lane + 64] + b1b;
        float acc1a = U[i1 * 128 + lane] + V[j1 * 128 + lane] + b1a;
        float acc1b = U[i1 * 128 + lane + 64] + V[j1 * 128 + lane + 64] + b1b;
#pragma unroll 8
        for (int k = 0; k < 64; ++k) {
            float w_a = Wc[k * 128 + lane];
            float w_b = Wc[k * 128 + lane + 64];
            float dk0 = readlane_f(d0a, k);
            float dk1 = readlane_f(d1a, k);
            acc0a += dk0 * w_a; acc0b += dk0 * w_b;
            acc1a += dk1 * w_a; acc1b += dk1 * w_b;
        }
#pragma unroll 8
        for (int k = 0; k < 64; ++k) {
            float w_a = Wc[(64 + k) * 128 + lane];
            float w_b = Wc[(64 + k) * 128 + lane + 64];
            float dk0 = readlane_f(d0b, k);
            float dk1 = readlane_f(d1b, k);
            acc0a += dk0 * w_a; acc0b += dk0 * w_b;
            acc1a += dk1 * w_a; acc1b += dk1 * w_b;
        }
        float s0 = fmaxf(acc0a, 0.f) * w2a + fmaxf(acc0b, 0.f) * w2b;
        float s1 = fmaxf(acc1a, 0.f) * w2a + fmaxf(acc1b, 0.f) * w2b;
#pragma unroll
        for (int off = 32; off; off >>= 1) {
            s0 += __shfl_xor(s0, off, 64);
            s1 += __shfl_xor(s1, off, 64);
        }
        if (lane == 0) {
            out[p0] = s0 + b2v;
            if (has1) out[p1] = s1 + b2v;
        }
    }
}

extern "C" void kernel_launch(void* const* d_in, const int* in_sizes, int n_in,
                              void* d_out, int out_size, void* d_ws, size_t ws_size,
                              hipStream_t stream) {
    const float* x  = (const float*)d_in[0];
    const int*   eI = (const int*)d_in[1];
    const int*   eD = (const int*)d_in[2];
    const int*   eL = (const int*)d_in[3];
    const float* Wconv = (const float*)d_in[4];
    const float* bconv = (const float*)d_in[5];
    const float* W1 = (const float*)d_in[6];
    const float* b1 = (const float*)d_in[7];
    const float* W2 = (const float*)d_in[8];
    const float* b2 = (const float*)d_in[9];

    int N = in_sizes[0] / 256;
    int E = in_sizes[1] / 2;
    int P = in_sizes[3] / 2;

    float* ws = (float*)d_ws;
    float* xl = ws;                       // N*128
    float* AI = xl + (long)N * 128;       // N*128 (later reused as U)
    float* AD = AI + (long)N * 128;       // N*128 (later reused as V)
    float* zb = AD + (long)N * 128;       // N*128
    float* dI = zb + (long)N * 128;       // N (deg -> dinv in place)
    float* dD = dI + N;                   // N
    float* out = (float*)d_out;

    dim3 g1(128 / 64, (N + 63) / 64);
    // xl = x @ W_conv
    gemm64_f32<<<g1, 256, 0, stream>>>(x, Wconv, xl, N, 256, 128);

    deg_init<<<(N + 255) / 256, 256, 0, stream>>>(dI, dD, N);
    count_edges<<<(E + 255) / 256, 256, 0, stream>>>(eI + E, dI, E);
    count_edges<<<(E + 255) / 256, 256, 0, stream>>>(eD + E, dD, E);
    to_dinv<<<(N + 255) / 256, 256, 0, stream>>>(dI, dD, N);

    init_self<<<((N * 32) + 255) / 256, 256, 0, stream>>>(xl, dI, dD, AI, AD, N);
    scatter_edges<<<((E * 32) + 255) / 256, 256, 0, stream>>>(xl, eI, eI + E, dI, AI, E);
    scatter_edges<<<((E * 32) + 255) / 256, 256, 0, stream>>>(xl, eD, eD + E, dD, AD, E);
    z_combine<<<((N * 32) + 255) / 256, 256, 0, stream>>>(AI, AD, bconv, zb, N);

    // U = z @ W1[0:128,:]  -> overwrite AI;  V = z @ W1[128:256,:] -> overwrite AD
    gemm64_f32<<<g1, 256, 0, stream>>>(zb, W1, AI, N, 128, 128);
    gemm64_f32<<<g1, 256, 0, stream>>>(zb, W1 + 128 * 128, AD, N, 128, 128);

    decode_kernel<<<1024, 256, 0, stream>>>(AI, AD, zb, eL, eL + P, W1, b1, W2, b2, out, P);
}

// Round 2
// 1092.765 us; speedup vs baseline: 3.2450x; 3.2450x over previous
//
#include <hip/hip_runtime.h>

#define HD __device__ __forceinline__

HD float readlane_f(float v, int l) {
    return __int_as_float(__builtin_amdgcn_readlane(__float_as_int(v), l));
}

// ---------------- generic fp32 tiled GEMM: C[M,N] = A[M,K] @ B[K,N] ----------------
// requires N % 64 == 0, K % 16 == 0
__global__ __launch_bounds__(256) void gemm64_f32(const float* __restrict__ A,
                                                  const float* __restrict__ B,
                                                  float* __restrict__ C,
                                                  int M, int K, int N) {
    __shared__ float As[64 * 16];
    __shared__ float Bs[16 * 64];
    int tx = threadIdx.x & 15, ty = threadIdx.x >> 4;
    int rowBase = blockIdx.y * 64, colBase = blockIdx.x * 64;
    float acc[4][4] = {};
    for (int k0 = 0; k0 < K; k0 += 16) {
        for (int i = threadIdx.x; i < 64 * 16; i += 256) {
            int r = i >> 4, c = i & 15;
            int gr = rowBase + r;
            As[i] = (gr < M) ? A[(long)gr * K + k0 + c] : 0.f;
        }
        for (int i = threadIdx.x; i < 16 * 64; i += 256) {
            int r = i >> 6, c = i & 63;
            Bs[i] = B[(long)(k0 + r) * N + colBase + c];
        }
        __syncthreads();
#pragma unroll
        for (int kk = 0; kk < 16; ++kk) {
            float a[4], b[4];
#pragma unroll
            for (int i = 0; i < 4; ++i) a[i] = As[(ty * 4 + i) * 16 + kk];
#pragma unroll
            for (int j = 0; j < 4; ++j) b[j] = Bs[kk * 64 + tx * 4 + j];
#pragma unroll
            for (int i = 0; i < 4; ++i)
#pragma unroll
                for (int j = 0; j < 4; ++j) acc[i][j] += a[i] * b[j];
        }
        __syncthreads();
    }
    for (int i = 0; i < 4; ++i) {
        int gr = rowBase + ty * 4 + i;
        if (gr < M)
            for (int j = 0; j < 4; ++j)
                C[(long)gr * N + colBase + tx * 4 + j] = acc[i][j];
    }
}

// ---------------- CSR build ----------------
__global__ void zero_ints(int* p, int n) {
    int i = blockIdx.x * 256 + threadIdx.x;
    if (i < n) p[i] = 0;
}

// count degrees of both graphs into cnt[0..N) and cnt[N..2N)
__global__ void count_deg(const int* __restrict__ dstI, const int* __restrict__ dstD,
                          int* cnt, int N, int E) {
    int e = blockIdx.x * 256 + threadIdx.x;
    if (e < E) {
        atomicAdd(&cnt[dstI[e]], 1);
        atomicAdd(&cnt[N + dstD[e]], 1);
    }
}

__global__ void make_dinv(const int* __restrict__ cnt, float* dI, float* dD, int N) {
    int i = blockIdx.x * 256 + threadIdx.x;
    if (i < N) {
        dI[i] = rsqrtf((float)(cnt[i] + 1));       // +1 self loop
        dD[i] = rsqrtf((float)(cnt[N + i] + 1));
    }
}

// exclusive scan over n2 elements, 256 per block
__global__ void scan_partial(const int* __restrict__ cnt, int* partials, int n2) {
    __shared__ int sdata[256];
    int i = blockIdx.x * 256 + threadIdx.x;
    sdata[threadIdx.x] = (i < n2) ? cnt[i] : 0;
    __syncthreads();
    for (int s = 128; s > 0; s >>= 1) {
        if (threadIdx.x < s) sdata[threadIdx.x] += sdata[threadIdx.x + s];
        __syncthreads();
    }
    if (threadIdx.x == 0) partials[blockIdx.x] = sdata[0];
}

__global__ void scan_partials_excl(int* partials, int nb) {
    if (blockIdx.x == 0 && threadIdx.x == 0) {
        int acc = 0;
        for (int i = 0; i < nb; ++i) { int t = partials[i]; partials[i] = acc; acc += t; }
    }
}

__global__ void scan_final(const int* __restrict__ cnt, const int* __restrict__ partials,
                           int* off, int* cur, int n2) {
    __shared__ int sdata[256];
    int i = blockIdx.x * 256 + threadIdx.x;
    int v = (i < n2) ? cnt[i] : 0;
    sdata[threadIdx.x] = v;
    __syncthreads();
    for (int s = 1; s < 256; s <<= 1) {
        int t = (threadIdx.x >= s) ? sdata[threadIdx.x - s] : 0;
        __syncthreads();
        sdata[threadIdx.x] += t;
        __syncthreads();
    }
    int excl = sdata[threadIdx.x] - v + partials[blockIdx.x];
    if (i < n2) { off[i] = excl; cur[i] = excl; }
}

// bucket the src indices by destination (both graphs; D half offset by N in cur)
__global__ void fill_csr(const int* __restrict__ srcI, const int* __restrict__ dstI,
                         const int* __restrict__ srcD, const int* __restrict__ dstD,
                         int* cur, int* srcs, int N, int E) {
    int e = blockIdx.x * 256 + threadIdx.x;
    if (e < E) {
        int pos = atomicAdd(&cur[dstI[e]], 1);
        srcs[pos] = srcI[e];
        int pos2 = atomicAdd(&cur[N + dstD[e]], 1);
        srcs[pos2] = srcD[e];
    }
}

// y = dinv * xl for both graphs in one pass
__global__ void scale_y(const float* __restrict__ xl, const float* __restrict__ dI,
                        const float* __restrict__ dD, float* yI, float* yD, int N) {
    int t = blockIdx.x * 256 + threadIdx.x;
    int i = t >> 5, f4 = t & 31;
    if (i >= N) return;
    float4 v = ((const float4*)(xl + (long)i * 128))[f4];
    float a = dI[i], b = dD[i];
    float4 vi = {v.x * a, v.y * a, v.z * a, v.w * a};
    float4 vd = {v.x * b, v.y * b, v.z * b, v.w * b};
    ((float4*)(yI + (long)i * 128))[f4] = vi;
    ((float4*)(yD + (long)i * 128))[f4] = vd;
}

// one wave per node: gather both graphs' messages, combine into z
__global__ __launch_bounds__(256) void gather_combine(
    const float* __restrict__ yI, const float* __restrict__ yD,
    const int* __restrict__ off, const int* __restrict__ srcs,
    const float* __restrict__ dI, const float* __restrict__ dD,
    const float* __restrict__ bconv, float* __restrict__ z, int N, int E2) {
    int d = blockIdx.x * 4 + (threadIdx.x >> 6);
    int lane = threadIdx.x & 63;
    if (d >= N) return;
    const float2* yI2 = (const float2*)yI;
    const float2* yD2 = (const float2*)yD;
    float2 accI = yI2[(long)d * 64 + lane];   // self-loop term
    float2 accD = yD2[(long)d * 64 + lane];
    int sI = off[d], eI = off[d + 1];                       // off[N] == E (valid sentinel)
    int sD = off[N + d], eD = (d == N - 1) ? E2 : off[N + d + 1];
    for (int k0 = sI; k0 < eI; k0 += 64) {
        int nk = min(64, eI - k0);
        int sidx = (lane < nk) ? srcs[k0 + lane] : 0;
        for (int k = 0; k < nk; ++k) {
            int s = __builtin_amdgcn_readlane(sidx, k);
            float2 v = yI2[(long)s * 64 + lane];
            accI.x += v.x; accI.y += v.y;
        }
    }
    for (int k0 = sD; k0 < eD; k0 += 64) {
        int nk = min(64, eD - k0);
        int sidx = (lane < nk) ? srcs[k0 + lane] : 0;
        for (int k = 0; k < nk; ++k) {
            int s = __builtin_amdgcn_readlane(sidx, k);
            float2 v = yD2[(long)s * 64 + lane];
            accD.x += v.x; accD.y += v.y;
        }
    }
    float aI = dI[d], aD = dD[d];
    float2 b = ((const float2*)bconv)[lane];
    float2 r;
    r.x = fmaxf(aI * accI.x + b.x, 0.f) + fmaxf(aD * accD.x + b.x, 0.f);
    r.y = fmaxf(aI * accI.y + b.y, 0.f) + fmaxf(aD * accD.y + b.y, 0.f);
    ((float2*)z)[(long)d * 64 + lane] = r;
}

// ---------------- decode ----------------
__global__ __launch_bounds__(256) void decode_kernel(
    const float* __restrict__ U, const float* __restrict__ V, const float* __restrict__ z,
    const int* __restrict__ ei, const int* __restrict__ ej,
    const float* __restrict__ W1, const float* __restrict__ b1,
    const float* __restrict__ W2, const float* __restrict__ b2,
    float* __restrict__ out, int P) {
    __shared__ float Wc[128 * 128];
    for (int i = threadIdx.x; i < 128 * 128; i += 256) Wc[i] = W1[256 * 128 + i];
    __syncthreads();
    int lane = threadIdx.x & 63;
    int wid = blockIdx.x * 4 + (threadIdx.x >> 6);
    int nw = gridDim.x * 4;
    float b1a = b1[lane], b1b = b1[lane + 64];
    float w2a = W2[lane], w2b = W2[lane + 64];
    float b2v = b2[0];
    for (int base = wid * 2; base < P; base += nw * 2) {
        int p0 = base, p1 = base + 1;
        bool has1 = p1 < P;
        int i0 = ei[p0], j0 = ej[p0];
        int i1 = has1 ? ei[p1] : i0, j1 = has1 ? ej[p1] : j0;
        float zi0a = z[i0 * 128 + lane], zi0b = z[i0 * 128 + lane + 64];
        float zj0a = z[j0 * 128 + lane], zj0b = z[j0 * 128 + lane + 64];
        float zi1a = z[i1 * 128 + lane], zi1b = z[i1 * 128 + lane + 64];
        float zj1a = z[j1 * 128 + lane], zj1b = z[j1 * 128 + lane + 64];
        float d0a = fabsf(zi0a - zj0a), d0b = fabsf(zi0b - zj0b);
        float d1a = fabsf(zi1a - zj1a), d1b = fabsf(zi1b - zj1b);
        float acc0a = U[i0 * 128 + lane] + V[j0 * 128 + lane] + b1a;
        float acc0b = U[i0 * 128 + lane + 64] + V[j0 * 128 + lane + 64] + b1b;
        float acc1a = U[i1 * 128 + lane] + V[j1 * 128 + lane] + b1a;
        float acc1b = U[i1 * 128 + lane + 64] + V[j1 * 128 + lane + 64] + b1b;
#pragma unroll 8
        for (int k = 0; k < 64; ++k) {
            float w_a = Wc[k * 128 + lane];
            float w_b = Wc[k * 128 + lane + 64];
            float dk0 = readlane_f(d0a, k);
            float dk1 = readlane_f(d1a, k);
            acc0a += dk0 * w_a; acc0b += dk0 * w_b;
            acc1a += dk1 * w_a; acc1b += dk1 * w_b;
        }
#pragma unroll 8
        for (int k = 0; k < 64; ++k) {
            float w_a = Wc[(64 + k) * 128 + lane];
            float w_b = Wc[(64 + k) * 128 + lane + 64];
            float dk0 = readlane_f(d0b, k);
            float dk1 = readlane_f(d1b, k);
            acc0a += dk0 * w_a; acc0b += dk0 * w_b;
            acc1a += dk1 * w_a; acc1b += dk1 * w_b;
        }
        float s0 = fmaxf(acc0a, 0.f) * w2a + fmaxf(acc0b, 0.f) * w2b;
        float s1 = fmaxf(acc1a, 0.f) * w2a + fmaxf(acc1b, 0.f) * w2b;
#pragma unroll
        for (int off = 32; off; off >>= 1) {
            s0 += __shfl_xor(s0, off, 64);
            s1 += __shfl_xor(s1, off, 64);
        }
        if (lane == 0) {
            out[p0] = s0 + b2v;
            if (has1) out[p1] = s1 + b2v;
        }
    }
}

extern "C" void kernel_launch(void* const* d_in, const int* in_sizes, int n_in,
                              void* d_out, int out_size, void* d_ws, size_t ws_size,
                              hipStream_t stream) {
    const float* x  = (const float*)d_in[0];
    const int*   eI = (const int*)d_in[1];
    const int*   eD = (const int*)d_in[2];
    const int*   eL = (const int*)d_in[3];
    const float* Wconv = (const float*)d_in[4];
    const float* bconv = (const float*)d_in[5];
    const float* W1 = (const float*)d_in[6];
    const float* b1 = (const float*)d_in[7];
    const float* W2 = (const float*)d_in[8];
    const float* b2 = (const float*)d_in[9];

    int N = in_sizes[0] / 256;
    int E = in_sizes[1] / 2;
    int P = in_sizes[3] / 2;
    long NH = (long)N * 128;

    // ---- workspace layout ----
    float* ws = (float*)d_ws;
    float* buf0 = ws;             // xl, later z
    float* buf1 = buf0 + NH;      // yI, later U
    float* buf2 = buf1 + NH;      // yD, later V
    float* dI = buf2 + NH;        // N
    float* dD = dI + N;           // N
    int* iws = (int*)(dD + N);
    int n2 = 2 * N;
    int* cnt = iws;               // 2N
    int* off = cnt + n2;          // 2N
    int* cur = off + n2;          // 2N
    int nb = (n2 + 255) / 256;
    int* partials = cur + n2;     // nb
    int* srcs = partials + ((nb + 63) & ~63);  // 2E
    float* out = (float*)d_out;

    float* xl = buf0;
    float* yI = buf1;
    float* yD = buf2;
    float* z  = buf0;   // aliases xl (xl dead after scale_y)
    float* U  = buf1;   // aliases yI (dead after gather)
    float* V  = buf2;   // aliases yD

    dim3 g1(128 / 64, (N + 63) / 64);
    // xl = x @ W_conv
    gemm64_f32<<<g1, 256, 0, stream>>>(x, Wconv, xl, N, 256, 128);

    // ---- CSR build (overlaps nothing; tiny) ----
    zero_ints<<<(n2 + 255) / 256, 256, 0, stream>>>(cnt, n2);
    count_deg<<<(E + 255) / 256, 256, 0, stream>>>(eI + E, eD + E, cnt, N, E);
    make_dinv<<<(N + 255) / 256, 256, 0, stream>>>(cnt, dI, dD, N);
    scan_partial<<<nb, 256, 0, stream>>>(cnt, partials, n2);
    scan_partials_excl<<<1, 64, 0, stream>>>(partials, nb);
    scan_final<<<nb, 256, 0, stream>>>(cnt, partials, off, cur, n2);
    fill_csr<<<(E + 255) / 256, 256, 0, stream>>>(eI, eI + E, eD, eD + E, cur, srcs, N, E);

    // y = dinv * xl (both graphs)
    scale_y<<<((N * 32) + 255) / 256, 256, 0, stream>>>(xl, dI, dD, yI, yD, N);

    // gather + combine -> z
    gather_combine<<<(N + 3) / 4, 256, 0, stream>>>(yI, yD, off, srcs, dI, dD, bconv, z, N, 2 * E);

    // U = z @ W1[0:128,:], V = z @ W1[128:256,:]
    gemm64_f32<<<g1, 256, 0, stream>>>(z, W1, U, N, 128, 128);
    gemm64_f32<<<g1, 256, 0, stream>>>(z, W1 + 128 * 128, V, N, 128, 128);

    decode_kernel<<<1024, 256, 0, stream>>>(U, V, z, eL, eL + P, W1, b1, W2, b2, out, P);
}

// Round 3
// 716.086 us; speedup vs baseline: 4.9520x; 1.5260x over previous
//
#include <hip/hip_runtime.h>

typedef short short8 __attribute__((ext_vector_type(8)));
typedef float f32x4 __attribute__((ext_vector_type(4)));
typedef unsigned short ushort_t;
typedef unsigned int uint_t;

#define HD __device__ __forceinline__

HD ushort_t f2bf(float f) {  // round-to-nearest-even f32 -> bf16 bits
    uint_t u = __float_as_uint(f);
    uint_t r = (u + 0x7fffu + ((u >> 16) & 1u)) >> 16;
    return (ushort_t)r;
}
HD float bf2f(ushort_t h) { return __uint_as_float(((uint_t)h) << 16); }

// ---------------- generic fp32 tiled GEMM: C[M,N] = A[M,K] @ B[K,N] ----------------
__global__ __launch_bounds__(256) void gemm64_f32(const float* __restrict__ A,
                                                  const float* __restrict__ B,
                                                  float* __restrict__ C,
                                                  int M, int K, int N) {
    __shared__ float As[64 * 16];
    __shared__ float Bs[16 * 64];
    int tx = threadIdx.x & 15, ty = threadIdx.x >> 4;
    int rowBase = blockIdx.y * 64, colBase = blockIdx.x * 64;
    float acc[4][4] = {};
    for (int k0 = 0; k0 < K; k0 += 16) {
        for (int i = threadIdx.x; i < 64 * 16; i += 256) {
            int r = i >> 4, c = i & 15;
            int gr = rowBase + r;
            As[i] = (gr < M) ? A[(long)gr * K + k0 + c] : 0.f;
        }
        for (int i = threadIdx.x; i < 16 * 64; i += 256) {
            int r = i >> 6, c = i & 63;
            Bs[i] = B[(long)(k0 + r) * N + colBase + c];
        }
        __syncthreads();
#pragma unroll
        for (int kk = 0; kk < 16; ++kk) {
            float a[4], b[4];
#pragma unroll
            for (int i = 0; i < 4; ++i) a[i] = As[(ty * 4 + i) * 16 + kk];
#pragma unroll
            for (int j = 0; j < 4; ++j) b[j] = Bs[kk * 64 + tx * 4 + j];
#pragma unroll
            for (int i = 0; i < 4; ++i)
#pragma unroll
                for (int j = 0; j < 4; ++j) acc[i][j] += a[i] * b[j];
        }
        __syncthreads();
    }
    for (int i = 0; i < 4; ++i) {
        int gr = rowBase + ty * 4 + i;
        if (gr < M)
            for (int j = 0; j < 4; ++j)
                C[(long)gr * N + colBase + tx * 4 + j] = acc[i][j];
    }
}

// ---------------- CSR build ----------------
__global__ void zero_ints(int* p, int n) {
    int i = blockIdx.x * 256 + threadIdx.x;
    if (i < n) p[i] = 0;
}

__global__ void count_deg(const int* __restrict__ dstI, const int* __restrict__ dstD,
                          int* cnt, int N, int E) {
    int e = blockIdx.x * 256 + threadIdx.x;
    if (e < E) {
        atomicAdd(&cnt[dstI[e]], 1);
        atomicAdd(&cnt[N + dstD[e]], 1);
    }
}

__global__ void make_dinv(const int* __restrict__ cnt, float* dI, float* dD, int N) {
    int i = blockIdx.x * 256 + threadIdx.x;
    if (i < N) {
        dI[i] = rsqrtf((float)(cnt[i] + 1));
        dD[i] = rsqrtf((float)(cnt[N + i] + 1));
    }
}

__global__ void scan_partial(const int* __restrict__ cnt, int* partials, int n2) {
    __shared__ int sdata[256];
    int i = blockIdx.x * 256 + threadIdx.x;
    sdata[threadIdx.x] = (i < n2) ? cnt[i] : 0;
    __syncthreads();
    for (int s = 128; s > 0; s >>= 1) {
        if (threadIdx.x < s) sdata[threadIdx.x] += sdata[threadIdx.x + s];
        __syncthreads();
    }
    if (threadIdx.x == 0) partials[blockIdx.x] = sdata[0];
}

__global__ void scan_partials_excl(int* partials, int nb) {
    if (blockIdx.x == 0 && threadIdx.x == 0) {
        int acc = 0;
        for (int i = 0; i < nb; ++i) { int t = partials[i]; partials[i] = acc; acc += t; }
    }
}

__global__ void scan_final(const int* __restrict__ cnt, const int* __restrict__ partials,
                           int* off, int* cur, int n2) {
    __shared__ int sdata[256];
    int i = blockIdx.x * 256 + threadIdx.x;
    int v = (i < n2) ? cnt[i] : 0;
    sdata[threadIdx.x] = v;
    __syncthreads();
    for (int s = 1; s < 256; s <<= 1) {
        int t = (threadIdx.x >= s) ? sdata[threadIdx.x - s] : 0;
        __syncthreads();
        sdata[threadIdx.x] += t;
        __syncthreads();
    }
    int excl = sdata[threadIdx.x] - v + partials[blockIdx.x];
    if (i < n2) { off[i] = excl; cur[i] = excl; }
}

__global__ void fill_csr(const int* __restrict__ srcI, const int* __restrict__ dstI,
                         const int* __restrict__ srcD, const int* __restrict__ dstD,
                         int* cur, int* srcs, int N, int E) {
    int e = blockIdx.x * 256 + threadIdx.x;
    if (e < E) {
        int pos = atomicAdd(&cur[dstI[e]], 1);
        srcs[pos] = srcI[e];
        int pos2 = atomicAdd(&cur[N + dstD[e]], 1);
        srcs[pos2] = srcD[e];
    }
}

// y = dinv * xl for both graphs
__global__ void scale_y(const float* __restrict__ xl, const float* __restrict__ dI,
                        const float* __restrict__ dD, float* yI, float* yD, int N) {
    int t = blockIdx.x * 256 + threadIdx.x;
    int i = t >> 5, f4 = t & 31;
    if (i >= N) return;
    float4 v = ((const float4*)(xl + (long)i * 128))[f4];
    float a = dI[i], b = dD[i];
    float4 vi = {v.x * a, v.y * a, v.z * a, v.w * a};
    float4 vd = {v.x * b, v.y * b, v.z * b, v.w * b};
    ((float4*)(yI + (long)i * 128))[f4] = vi;
    ((float4*)(yD + (long)i * 128))[f4] = vd;
}

// one wave per node: gather both graphs' messages, combine into z
__global__ __launch_bounds__(256) void gather_combine(
    const float* __restrict__ yI, const float* __restrict__ yD,
    const int* __restrict__ off, const int* __restrict__ srcs,
    const float* __restrict__ dI, const float* __restrict__ dD,
    const float* __restrict__ bconv, float* __restrict__ z, int N, int E2) {
    int d = blockIdx.x * 4 + (threadIdx.x >> 6);
    int lane = threadIdx.x & 63;
    if (d >= N) return;
    const float2* yI2 = (const float2*)yI;
    const float2* yD2 = (const float2*)yD;
    float2 accI = yI2[(long)d * 64 + lane];
    float2 accD = yD2[(long)d * 64 + lane];
    int sI = off[d], eI = off[d + 1];
    int sD = off[N + d], eD = (d == N - 1) ? E2 : off[N + d + 1];
    for (int k0 = sI; k0 < eI; k0 += 64) {
        int nk = min(64, eI - k0);
        int sidx = (lane < nk) ? srcs[k0 + lane] : 0;
        for (int k = 0; k < nk; ++k) {
            int s = __builtin_amdgcn_readlane(sidx, k);
            float2 v = yI2[(long)s * 64 + lane];
            accI.x += v.x; accI.y += v.y;
        }
    }
    for (int k0 = sD; k0 < eD; k0 += 64) {
        int nk = min(64, eD - k0);
        int sidx = (lane < nk) ? srcs[k0 + lane] : 0;
        for (int k = 0; k < nk; ++k) {
            int s = __builtin_amdgcn_readlane(sidx, k);
            float2 v = yD2[(long)s * 64 + lane];
            accD.x += v.x; accD.y += v.y;
        }
    }
    float aI = dI[d], aD = dD[d];
    float2 b = ((const float2*)bconv)[lane];
    float2 r;
    r.x = fmaxf(aI * accI.x + b.x, 0.f) + fmaxf(aD * accD.x + b.x, 0.f);
    r.y = fmaxf(aI * accI.y + b.y, 0.f) + fmaxf(aD * accD.y + b.y, 0.f);
    ((float2*)z)[(long)d * 64 + lane] = r;
}

// ---------------- decode prep: W1c^T -> bf16 ----------------
// w1ct[n*128 + k] = bf16( W1[(256+k)*128 + n] )
__global__ void prep_w1ct(const float* __restrict__ W1, ushort_t* __restrict__ w1ct) {
    int idx = blockIdx.x * 256 + threadIdx.x;
    if (idx >= 128 * 128) return;
    int n = idx >> 7, k = idx & 127;
    w1ct[idx] = f2bf(W1[(256 + k) * 128 + n]);
}

// ---------------- decode via MFMA ----------------
// block: 4 waves, 64 pairs (16/wave). A = hi/lo-split bf16 of |zi-zj| (fp32-exact
// to ~2^-17), B = bf16(W1c^T) staged in LDS. Epilogue gathers fp32 U,V.
__global__ __launch_bounds__(256) void decode_mfma(
    const float* __restrict__ z, const float* __restrict__ U, const float* __restrict__ V,
    const int* __restrict__ ei, const int* __restrict__ ej,
    const ushort_t* __restrict__ w1ct,
    const float* __restrict__ b1, const float* __restrict__ W2, const float* __restrict__ b2,
    float* __restrict__ out, int P) {
    __shared__ ushort_t Wlds[128][136];   // padded: 272 B row stride, bank-friendly
    __shared__ ushort_t Ahi[4][16][136];
    __shared__ ushort_t Alo[4][16][136];
    int tid = threadIdx.x;
    // stage W1c^T (8192 dwords)
    const uint_t* w32 = (const uint_t*)w1ct;
    for (int t = tid; t < 8192; t += 256) {
        int n = t >> 6, c2 = t & 63;
        *(uint_t*)&Wlds[n][c2 * 2] = w32[t];
    }
    int lane = tid & 63, w = tid >> 6;
    int r = lane & 15, q = lane >> 4;
    int base = blockIdx.x * 64 + w * 16;
    int iv = 0, jv = 0;
    if (base < P) {
        if (lane < 16) {
            int p = min(base + lane, P - 1);
            iv = ei[p]; jv = ej[p];
        }
        const float2* z2 = (const float2*)z;
#pragma unroll 4
        for (int p = 0; p < 16; ++p) {
            int ip = __builtin_amdgcn_readlane(iv, p);
            int jp = __builtin_amdgcn_readlane(jv, p);
            float2 a = z2[(long)ip * 64 + lane];
            float2 b = z2[(long)jp * 64 + lane];
            float d0 = fabsf(a.x - b.x), d1 = fabsf(a.y - b.y);
            ushort_t h0 = f2bf(d0), h1 = f2bf(d1);
            float r0 = d0 - bf2f(h0), r1 = d1 - bf2f(h1);
            ushort_t l0 = f2bf(r0), l1 = f2bf(r1);
            *(uint_t*)&Ahi[w][p][lane * 2] = (uint_t)h0 | ((uint_t)h1 << 16);
            *(uint_t*)&Alo[w][p][lane * 2] = (uint_t)l0 | ((uint_t)l1 << 16);
        }
    }
    __syncthreads();
    if (base >= P) return;

    f32x4 acc[8] = {};
    short8 afh[4], afl[4];
#pragma unroll
    for (int kk = 0; kk < 4; ++kk) {
        afh[kk] = *(const short8*)&Ahi[w][r][kk * 32 + q * 8];
        afl[kk] = *(const short8*)&Alo[w][r][kk * 32 + q * 8];
    }
#pragma unroll
    for (int t = 0; t < 8; ++t) {
#pragma unroll
        for (int kk = 0; kk < 4; ++kk) {
            short8 bfr = *(const short8*)&Wlds[16 * t + r][kk * 32 + q * 8];
            acc[t] = __builtin_amdgcn_mfma_f32_16x16x32_bf16(afl[kk], bfr, acc[t], 0, 0, 0);
            acc[t] = __builtin_amdgcn_mfma_f32_16x16x32_bf16(afh[kk], bfr, acc[t], 0, 0, 0);
        }
    }

    // epilogue: h = acc + U[i] + V[j] + b1 ; out = relu(h) @ W2 + b2
    float b2v = b2[0];
    float b1c[8], w2c[8];
#pragma unroll
    for (int t = 0; t < 8; ++t) {
        int col = 16 * t + r;
        b1c[t] = b1[col];
        w2c[t] = W2[col];
    }
#pragma unroll
    for (int r2 = 0; r2 < 4; ++r2) {
        int row = q * 4 + r2;             // C layout: row = (lane>>4)*4 + reg
        int irow = __shfl(iv, row, 64);
        int jrow = __shfl(jv, row, 64);
        float s = 0.f;
#pragma unroll
        for (int t = 0; t < 8; ++t) {
            int col = 16 * t + r;          // C layout: col = lane&15 (+16t)
            float h = acc[t][r2] + U[(long)irow * 128 + col] + V[(long)jrow * 128 + col] + b1c[t];
            s += fmaxf(h, 0.f) * w2c[t];
        }
        s += __shfl_xor(s, 1, 64);
        s += __shfl_xor(s, 2, 64);
        s += __shfl_xor(s, 4, 64);
        s += __shfl_xor(s, 8, 64);
        int gp = base + row;
        if (r == 0 && gp < P) out[gp] = s + b2v;
    }
}

extern "C" void kernel_launch(void* const* d_in, const int* in_sizes, int n_in,
                              void* d_out, int out_size, void* d_ws, size_t ws_size,
                              hipStream_t stream) {
    const float* x  = (const float*)d_in[0];
    const int*   eI = (const int*)d_in[1];
    const int*   eD = (const int*)d_in[2];
    const int*   eL = (const int*)d_in[3];
    const float* Wconv = (const float*)d_in[4];
    const float* bconv = (const float*)d_in[5];
    const float* W1 = (const float*)d_in[6];
    const float* b1 = (const float*)d_in[7];
    const float* W2 = (const float*)d_in[8];
    const float* b2 = (const float*)d_in[9];

    int N = in_sizes[0] / 256;
    int E = in_sizes[1] / 2;
    int P = in_sizes[3] / 2;
    long NH = (long)N * 128;

    float* ws = (float*)d_ws;
    float* buf0 = ws;             // xl, later z
    float* buf1 = buf0 + NH;      // yI, later U
    float* buf2 = buf1 + NH;      // yD, later V
    float* dI = buf2 + NH;
    float* dD = dI + N;
    int* iws = (int*)(dD + N);
    int n2 = 2 * N;
    int* cnt = iws;               // 2N
    int* off = cnt + n2;          // 2N
    int* cur = off + n2;          // 2N
    int nb = (n2 + 255) / 256;
    int* partials = cur + n2;     // nb
    int* srcs = partials + ((nb + 63) & ~63);  // 2E
    ushort_t* w1ct = (ushort_t*)(srcs + 2 * (long)E);  // 16384 bf16
    float* out = (float*)d_out;

    float* xl = buf0;
    float* yI = buf1;
    float* yD = buf2;
    float* z  = buf0;
    float* U  = buf1;
    float* V  = buf2;

    dim3 g1(128 / 64, (N + 63) / 64);
    gemm64_f32<<<g1, 256, 0, stream>>>(x, Wconv, xl, N, 256, 128);

    zero_ints<<<(n2 + 255) / 256, 256, 0, stream>>>(cnt, n2);
    count_deg<<<(E + 255) / 256, 256, 0, stream>>>(eI + E, eD + E, cnt, N, E);
    make_dinv<<<(N + 255) / 256, 256, 0, stream>>>(cnt, dI, dD, N);
    scan_partial<<<nb, 256, 0, stream>>>(cnt, partials, n2);
    scan_partials_excl<<<1, 64, 0, stream>>>(partials, nb);
    scan_final<<<nb, 256, 0, stream>>>(cnt, partials, off, cur, n2);
    fill_csr<<<(E + 255) / 256, 256, 0, stream>>>(eI, eI + E, eD, eD + E, cur, srcs, N, E);

    prep_w1ct<<<64, 256, 0, stream>>>(W1, w1ct);

    scale_y<<<((N * 32) + 255) / 256, 256, 0, stream>>>(xl, dI, dD, yI, yD, N);
    gather_combine<<<(N + 3) / 4, 256, 0, stream>>>(yI, yD, off, srcs, dI, dD, bconv, z, N, 2 * E);

    gemm64_f32<<<g1, 256, 0, stream>>>(z, W1, U, N, 128, 128);
    gemm64_f32<<<g1, 256, 0, stream>>>(z, W1 + 128 * 128, V, N, 128, 128);

    decode_mfma<<<(P + 63) / 64, 256, 0, stream>>>(z, U, V, eL, eL + P, w1ct,
                                                   b1, W2, b2, out, P);
}

// Round 4
// 586.393 us; speedup vs baseline: 6.0472x; 1.2212x over previous
//
#include <hip/hip_runtime.h>

typedef short short8 __attribute__((ext_vector_type(8)));
typedef float f32x4 __attribute__((ext_vector_type(4)));
typedef float f32x16 __attribute__((ext_vector_type(16)));
typedef unsigned short ushort_t;
typedef unsigned int uint_t;

#define HD __device__ __forceinline__

HD ushort_t f2bf(float f) {  // round-to-nearest-even f32 -> bf16 bits
    uint_t u = __float_as_uint(f);
    uint_t r = (u + 0x7fffu + ((u >> 16) & 1u)) >> 16;
    return (ushort_t)r;
}
HD float bf2f(ushort_t h) { return __uint_as_float(((uint_t)h) << 16); }
HD float readlane_f(float v, int l) {
    return __int_as_float(__builtin_amdgcn_readlane(__float_as_int(v), l));
}

// ---------------- MFMA hi/lo split GEMM: C[M,Ntot] = A[M,K] @ B ----------------
// B supplied pre-transposed+bf16-split: Bth/Btl[n][k] (n = global col, row stride K).
// Block tile 128x128, KT=64, 4 waves (wave w = rows w*32..w*32+31, all 128 cols).
// 3 MFMA products (AhBh + AlBh + AhBl) -> ~fp32 accuracy.
__global__ __launch_bounds__(256) void gemm_mfma_hilo(
    const float* __restrict__ A, const ushort_t* __restrict__ Bth,
    const ushort_t* __restrict__ Btl, float* __restrict__ C,
    int M, int K, int Ntot) {
    __shared__ ushort_t Ah[128][72], Al[128][72], Bh[128][72], Bl[128][72];
    int tid = threadIdx.x;
    int lane = tid & 63, w = tid >> 6;
    int row0 = blockIdx.x * 128;
    int col0 = blockIdx.y * 128;
    int cl = lane & 31, hi = lane >> 5;
    f32x16 acc[4] = {};
    for (int k0 = 0; k0 < K; k0 += 64) {
        // stage A tile (fp32 -> hi/lo bf16), [128 rows][64 k]
        for (int e = tid; e < 4096; e += 256) {
            int r = e >> 5, k2 = e & 31;
            int gr = row0 + r;
            float2 v = {0.f, 0.f};
            if (gr < M) v = *(const float2*)&A[(long)gr * K + k0 + k2 * 2];
            ushort_t h0 = f2bf(v.x); ushort_t l0 = f2bf(v.x - bf2f(h0));
            ushort_t h1 = f2bf(v.y); ushort_t l1 = f2bf(v.y - bf2f(h1));
            *(uint_t*)&Ah[r][k2 * 2] = (uint_t)h0 | ((uint_t)h1 << 16);
            *(uint_t*)&Al[r][k2 * 2] = (uint_t)l0 | ((uint_t)l1 << 16);
        }
        // stage B tile (already bf16 hi/lo in global)
        for (int e = tid; e < 4096; e += 256) {
            int n = e >> 5, k2 = e & 31;
            const uint_t* ph = (const uint_t*)&Bth[(long)(col0 + n) * K + k0];
            const uint_t* pl = (const uint_t*)&Btl[(long)(col0 + n) * K + k0];
            *(uint_t*)&Bh[n][k2 * 2] = ph[k2];
            *(uint_t*)&Bl[n][k2 * 2] = pl[k2];
        }
        __syncthreads();
        int arow = w * 32 + cl;
#pragma unroll
        for (int kk = 0; kk < 4; ++kk) {
            int koff = kk * 16 + hi * 8;
            short8 a_h = *(const short8*)&Ah[arow][koff];
            short8 a_l = *(const short8*)&Al[arow][koff];
#pragma unroll
            for (int nf = 0; nf < 4; ++nf) {
                int bcol = nf * 32 + cl;
                short8 b_h = *(const short8*)&Bh[bcol][koff];
                short8 b_l = *(const short8*)&Bl[bcol][koff];
                acc[nf] = __builtin_amdgcn_mfma_f32_32x32x16_bf16(a_h, b_h, acc[nf], 0, 0, 0);
                acc[nf] = __builtin_amdgcn_mfma_f32_32x32x16_bf16(a_l, b_h, acc[nf], 0, 0, 0);
                acc[nf] = __builtin_amdgcn_mfma_f32_32x32x16_bf16(a_h, b_l, acc[nf], 0, 0, 0);
            }
        }
        __syncthreads();
    }
    // C layout (32x32 mfma, m74/m101): col = lane&31, row = (reg&3)+8*(reg>>2)+4*(lane>>5)
#pragma unroll
    for (int nf = 0; nf < 4; ++nf) {
#pragma unroll
        for (int reg = 0; reg < 16; ++reg) {
            int crow = (reg & 3) + 8 * (reg >> 2) + 4 * hi + w * 32;
            int gr = row0 + crow;
            if (gr < M) C[(long)gr * Ntot + col0 + nf * 32 + cl] = acc[nf][reg];
        }
    }
}

// ---------------- weight prep ----------------
// Bt[n][k] = bf16 hi/lo of Wconv[k*128+n]   (n<128, k<256)
__global__ void prep_bt_conv(const float* __restrict__ Wc, ushort_t* bh, ushort_t* bl) {
    int idx = blockIdx.x * 256 + threadIdx.x;
    if (idx >= 128 * 256) return;
    int n = idx >> 8, k = idx & 255;
    float v = Wc[k * 128 + n];
    ushort_t h = f2bf(v);
    bh[idx] = h;
    bl[idx] = f2bf(v - bf2f(h));
}

// Bt[n][k] for combined [W1a | W1b]: n<128 -> W1[k*128+n]; n>=128 -> W1[(128+k)*128+n-128]
__global__ void prep_bt_uv(const float* __restrict__ W1, ushort_t* bh, ushort_t* bl) {
    int idx = blockIdx.x * 256 + threadIdx.x;
    if (idx >= 256 * 128) return;
    int n = idx >> 7, k = idx & 127;
    float v = (n < 128) ? W1[k * 128 + n] : W1[(128 + k) * 128 + (n - 128)];
    ushort_t h = f2bf(v);
    bh[idx] = h;
    bl[idx] = f2bf(v - bf2f(h));
}

// w1ct[n*128 + k] = bf16( W1[(256+k)*128 + n] )   (decode B operand)
__global__ void prep_w1ct(const float* __restrict__ W1, ushort_t* __restrict__ w1ct) {
    int idx = blockIdx.x * 256 + threadIdx.x;
    if (idx >= 128 * 128) return;
    int n = idx >> 7, k = idx & 127;
    w1ct[idx] = f2bf(W1[(256 + k) * 128 + n]);
}

// ---------------- CSR build ----------------
__global__ void zero_ints(int* p, int n) {
    int i = blockIdx.x * 256 + threadIdx.x;
    if (i < n) p[i] = 0;
}

__global__ void count_deg(const int* __restrict__ dstI, const int* __restrict__ dstD,
                          int* cnt, int N, int E) {
    int e = blockIdx.x * 256 + threadIdx.x;
    if (e < E) {
        atomicAdd(&cnt[dstI[e]], 1);
        atomicAdd(&cnt[N + dstD[e]], 1);
    }
}

__global__ void make_dinv(const int* __restrict__ cnt, float* dI, float* dD, int N) {
    int i = blockIdx.x * 256 + threadIdx.x;
    if (i < N) {
        dI[i] = rsqrtf((float)(cnt[i] + 1));
        dD[i] = rsqrtf((float)(cnt[N + i] + 1));
    }
}

__global__ void scan_partial(const int* __restrict__ cnt, int* partials, int n2) {
    __shared__ int sdata[256];
    int i = blockIdx.x * 256 + threadIdx.x;
    sdata[threadIdx.x] = (i < n2) ? cnt[i] : 0;
    __syncthreads();
    for (int s = 128; s > 0; s >>= 1) {
        if (threadIdx.x < s) sdata[threadIdx.x] += sdata[threadIdx.x + s];
        __syncthreads();
    }
    if (threadIdx.x == 0) partials[blockIdx.x] = sdata[0];
}

__global__ void scan_partials_excl(int* partials, int nb) {
    if (blockIdx.x == 0 && threadIdx.x == 0) {
        int acc = 0;
        for (int i = 0; i < nb; ++i) { int t = partials[i]; partials[i] = acc; acc += t; }
    }
}

__global__ void scan_final(const int* __restrict__ cnt, const int* __restrict__ partials,
                           int* off, int* cur, int n2) {
    __shared__ int sdata[256];
    int i = blockIdx.x * 256 + threadIdx.x;
    int v = (i < n2) ? cnt[i] : 0;
    sdata[threadIdx.x] = v;
    __syncthreads();
    for (int s = 1; s < 256; s <<= 1) {
        int t = (threadIdx.x >= s) ? sdata[threadIdx.x - s] : 0;
        __syncthreads();
        sdata[threadIdx.x] += t;
        __syncthreads();
    }
    int excl = sdata[threadIdx.x] - v + partials[blockIdx.x];
    if (i < n2) { off[i] = excl; cur[i] = excl; }
}

// bucket src + per-edge norm coefficient by destination
__global__ void fill_csr(const int* __restrict__ srcI, const int* __restrict__ dstI,
                         const int* __restrict__ srcD, const int* __restrict__ dstD,
                         const float* __restrict__ dI, const float* __restrict__ dD,
                         int* cur, int* srcs, float* coefs, int N, int E) {
    int e = blockIdx.x * 256 + threadIdx.x;
    if (e < E) {
        int s = srcI[e], d = dstI[e];
        int pos = atomicAdd(&cur[d], 1);
        srcs[pos] = s;
        coefs[pos] = dI[s] * dI[d];
        s = srcD[e]; d = dstD[e];
        pos = atomicAdd(&cur[N + d], 1);
        srcs[pos] = s;
        coefs[pos] = dD[s] * dD[d];
    }
}

// ---------------- gather: one wave per node, both graphs, 4-deep ILP ----------------
__global__ __launch_bounds__(256) void gather_combine2(
    const float* __restrict__ xl,
    const int* __restrict__ off, const int* __restrict__ srcs,
    const float* __restrict__ coefs,
    const float* __restrict__ dI, const float* __restrict__ dD,
    const float* __restrict__ bconv, float* __restrict__ z, int N, int E2) {
    int d = blockIdx.x * 4 + (threadIdx.x >> 6);
    int lane = threadIdx.x & 63;
    if (d >= N) return;
    const float2* x2 = (const float2*)xl;
    float2 xd = x2[(long)d * 64 + lane];
    float aI = dI[d], aD = dD[d];
    float2 accI, accD;
    {
        float c = aI * aI;
        accI.x = c * xd.x; accI.y = c * xd.y;
        c = aD * aD;
        accD.x = c * xd.x; accD.y = c * xd.y;
    }
#pragma unroll
    for (int g = 0; g < 2; ++g) {
        int s0 = (g == 0) ? off[d] : off[N + d];
        int e0 = (g == 0) ? off[d + 1] : ((d == N - 1) ? E2 : off[N + d + 1]);
        float2 a0 = {0.f, 0.f}, a1 = {0.f, 0.f}, a2 = {0.f, 0.f}, a3 = {0.f, 0.f};
        for (int k0 = s0; k0 < e0; k0 += 64) {
            int nk = min(64, e0 - k0);
            int sv = (lane < nk) ? srcs[k0 + lane] : 0;
            float cv = (lane < nk) ? coefs[k0 + lane] : 0.f;
            for (int k = 0; k < nk; k += 4) {
                int i0 = __builtin_amdgcn_readlane(sv, k);
                int i1 = __builtin_amdgcn_readlane(sv, k + 1);
                int i2 = __builtin_amdgcn_readlane(sv, k + 2);
                int i3 = __builtin_amdgcn_readlane(sv, k + 3);
                float c0 = readlane_f(cv, k);
                float c1 = readlane_f(cv, k + 1);
                float c2 = readlane_f(cv, k + 2);
                float c3 = readlane_f(cv, k + 3);
                float2 r0 = x2[(long)i0 * 64 + lane];
                float2 r1 = x2[(long)i1 * 64 + lane];
                float2 r2 = x2[(long)i2 * 64 + lane];
                float2 r3 = x2[(long)i3 * 64 + lane];
                a0.x = fmaf(c0, r0.x, a0.x); a0.y = fmaf(c0, r0.y, a0.y);
                a1.x = fmaf(c1, r1.x, a1.x); a1.y = fmaf(c1, r1.y, a1.y);
                a2.x = fmaf(c2, r2.x, a2.x); a2.y = fmaf(c2, r2.y, a2.y);
                a3.x = fmaf(c3, r3.x, a3.x); a3.y = fmaf(c3, r3.y, a3.y);
            }
        }
        float sx = (a0.x + a1.x) + (a2.x + a3.x);
        float sy = (a0.y + a1.y) + (a2.y + a3.y);
        if (g == 0) { accI.x += sx; accI.y += sy; }
        else        { accD.x += sx; accD.y += sy; }
    }
    float2 b = ((const float2*)bconv)[lane];
    float2 r;
    r.x = fmaxf(accI.x + b.x, 0.f) + fmaxf(accD.x + b.x, 0.f);
    r.y = fmaxf(accI.y + b.y, 0.f) + fmaxf(accD.y + b.y, 0.f);
    ((float2*)z)[(long)d * 64 + lane] = r;
}

// ---------------- decode via MFMA ----------------
__global__ __launch_bounds__(256) void decode_mfma(
    const float* __restrict__ z, const float* __restrict__ UV,
    const int* __restrict__ ei, const int* __restrict__ ej,
    const ushort_t* __restrict__ w1ct,
    const float* __restrict__ b1, const float* __restrict__ W2, const float* __restrict__ b2,
    float* __restrict__ out, int P) {
    __shared__ ushort_t Wlds[128][136];
    __shared__ ushort_t Ahi[4][16][136];
    __shared__ ushort_t Alo[4][16][136];
    int tid = threadIdx.x;
    const uint_t* w32 = (const uint_t*)w1ct;
    for (int t = tid; t < 8192; t += 256) {
        int n = t >> 6, c2 = t & 63;
        *(uint_t*)&Wlds[n][c2 * 2] = w32[t];
    }
    int lane = tid & 63, w = tid >> 6;
    int r = lane & 15, q = lane >> 4;
    int base = blockIdx.x * 64 + w * 16;
    int iv = 0, jv = 0;
    if (base < P) {
        if (lane < 16) {
            int p = min(base + lane, P - 1);
            iv = ei[p]; jv = ej[p];
        }
        const float2* z2 = (const float2*)z;
#pragma unroll 4
        for (int p = 0; p < 16; ++p) {
            int ip = __builtin_amdgcn_readlane(iv, p);
            int jp = __builtin_amdgcn_readlane(jv, p);
            float2 a = z2[(long)ip * 64 + lane];
            float2 b = z2[(long)jp * 64 + lane];
            float d0 = fabsf(a.x - b.x), d1 = fabsf(a.y - b.y);
            ushort_t h0 = f2bf(d0), h1 = f2bf(d1);
            float r0 = d0 - bf2f(h0), r1 = d1 - bf2f(h1);
            ushort_t l0 = f2bf(r0), l1 = f2bf(r1);
            *(uint_t*)&Ahi[w][p][lane * 2] = (uint_t)h0 | ((uint_t)h1 << 16);
            *(uint_t*)&Alo[w][p][lane * 2] = (uint_t)l0 | ((uint_t)l1 << 16);
        }
    }
    __syncthreads();
    if (base >= P) return;

    f32x4 acc[8] = {};
    short8 afh[4], afl[4];
#pragma unroll
    for (int kk = 0; kk < 4; ++kk) {
        afh[kk] = *(const short8*)&Ahi[w][r][kk * 32 + q * 8];
        afl[kk] = *(const short8*)&Alo[w][r][kk * 32 + q * 8];
    }
#pragma unroll
    for (int t = 0; t < 8; ++t) {
#pragma unroll
        for (int kk = 0; kk < 4; ++kk) {
            short8 bfr = *(const short8*)&Wlds[16 * t + r][kk * 32 + q * 8];
            acc[t] = __builtin_amdgcn_mfma_f32_16x16x32_bf16(afl[kk], bfr, acc[t], 0, 0, 0);
            acc[t] = __builtin_amdgcn_mfma_f32_16x16x32_bf16(afh[kk], bfr, acc[t], 0, 0, 0);
        }
    }

    float b2v = b2[0];
    float b1c[8], w2c[8];
#pragma unroll
    for (int t = 0; t < 8; ++t) {
        int col = 16 * t + r;
        b1c[t] = b1[col];
        w2c[t] = W2[col];
    }
#pragma unroll
    for (int r2 = 0; r2 < 4; ++r2) {
        int row = q * 4 + r2;
        int irow = __shfl(iv, row, 64);
        int jrow = __shfl(jv, row, 64);
        float s = 0.f;
#pragma unroll
        for (int t = 0; t < 8; ++t) {
            int col = 16 * t + r;
            float h = acc[t][r2] + UV[(long)irow * 256 + col] + UV[(long)jrow * 256 + 128 + col] + b1c[t];
            s += fmaxf(h, 0.f) * w2c[t];
        }
        s += __shfl_xor(s, 1, 64);
        s += __shfl_xor(s, 2, 64);
        s += __shfl_xor(s, 4, 64);
        s += __shfl_xor(s, 8, 64);
        int gp = base + row;
        if (r == 0 && gp < P) out[gp] = s + b2v;
    }
}

extern "C" void kernel_launch(void* const* d_in, const int* in_sizes, int n_in,
                              void* d_out, int out_size, void* d_ws, size_t ws_size,
                              hipStream_t stream) {
    const float* x  = (const float*)d_in[0];
    const int*   eI = (const int*)d_in[1];
    const int*   eD = (const int*)d_in[2];
    const int*   eL = (const int*)d_in[3];
    const float* Wconv = (const float*)d_in[4];
    const float* bconv = (const float*)d_in[5];
    const float* W1 = (const float*)d_in[6];
    const float* b1 = (const float*)d_in[7];
    const float* W2 = (const float*)d_in[8];
    const float* b2 = (const float*)d_in[9];

    int N = in_sizes[0] / 256;
    int E = in_sizes[1] / 2;
    int P = in_sizes[3] / 2;
    long NH = (long)N * 128;

    // ---- workspace layout ----
    float* ws = (float*)d_ws;
    float* xl = ws;                 // NH
    float* z  = xl + NH;            // NH
    float* UV = z + NH;             // 2*NH
    float* dI = UV + 2 * NH;        // N
    float* dD = dI + N;             // N
    int* iws = (int*)(dD + N);
    int n2 = 2 * N;
    int* cnt = iws;                 // 2N
    int* off = cnt + n2;            // 2N
    int* cur = off + n2;            // 2N
    int nb = (n2 + 255) / 256;
    int* partials = cur + n2;       // nb (align next to 64)
    int* srcs = partials + ((nb + 63) & ~63);       // 2E ints
    float* coefs = (float*)(srcs + 2 * (long)E);    // 2E floats
    ushort_t* w1ct = (ushort_t*)(coefs + 2 * (long)E);  // 16384
    ushort_t* btch = w1ct + 16384;                  // 32768
    ushort_t* btcl = btch + 32768;                  // 32768
    ushort_t* btuh = btcl + 32768;                  // 32768
    ushort_t* btul = btuh + 32768;                  // 32768
    float* out = (float*)d_out;

    // weight preps
    prep_bt_conv<<<128, 256, 0, stream>>>(Wconv, btch, btcl);
    prep_bt_uv<<<64 * 4 / 2, 256, 0, stream>>>(W1, btuh, btul);  // 128 blocks
    prep_w1ct<<<64, 256, 0, stream>>>(W1, w1ct);

    // xl = x @ W_conv   (MFMA split)
    dim3 gx((N + 127) / 128, 1);
    gemm_mfma_hilo<<<gx, 256, 0, stream>>>(x, btch, btcl, xl, N, 256, 128);

    // CSR build
    zero_ints<<<(n2 + 255) / 256, 256, 0, stream>>>(cnt, n2);
    count_deg<<<(E + 255) / 256, 256, 0, stream>>>(eI + E, eD + E, cnt, N, E);
    make_dinv<<<(N + 255) / 256, 256, 0, stream>>>(cnt, dI, dD, N);
    scan_partial<<<nb, 256, 0, stream>>>(cnt, partials, n2);
    scan_partials_excl<<<1, 64, 0, stream>>>(partials, nb);
    scan_final<<<nb, 256, 0, stream>>>(cnt, partials, off, cur, n2);
    fill_csr<<<(E + 255) / 256, 256, 0, stream>>>(eI, eI + E, eD, eD + E, dI, dD,
                                                  cur, srcs, coefs, N, E);

    // gather + combine -> z
    gather_combine2<<<(N + 3) / 4, 256, 0, stream>>>(xl, off, srcs, coefs, dI, dD,
                                                     bconv, z, N, 2 * E);

    // UV = z @ [W1a | W1b]  (one MFMA gemm, Ntot=256)
    dim3 guv((N + 127) / 128, 2);
    gemm_mfma_hilo<<<guv, 256, 0, stream>>>(z, btuh, btul, UV, N, 128, 256);

    decode_mfma<<<(P + 63) / 64, 256, 0, stream>>>(z, UV, eL, eL + P, w1ct,
                                                   b1, W2, b2, out, P);
}